// Round 1
// baseline (424.412 us; speedup 1.0000x reference)
//
#include <hip/hip_runtime.h>
#include <math.h>

#define NQ 32768      // queue size (rows of A = Q^T)
#define NC 1000       // clusters (cols of A)
#define NC4 250       // float4s per row

__device__ __forceinline__ float wredsum(float v) {
#pragma unroll
    for (int off = 32; off > 0; off >>= 1) v += __shfl_xor(v, off, 64);
    return v;
}

// Pass 1: cluster sums of exp(2*x) (no stabilizer needed; global scale cancels).
__global__ __launch_bounds__(256) void k_colsum_exp(const float* __restrict__ in,
                                                    float* __restrict__ S) {
    __shared__ float sacc[NC];
    for (int i = threadIdx.x; i < NC; i += 256) sacc[i] = 0.f;
    __syncthreads();
    const int lane = threadIdx.x & 63;
    const int nw = (gridDim.x * 256) >> 6;
    const int wave = (blockIdx.x * 256 + threadIdx.x) >> 6;
    float acc[16];
#pragma unroll
    for (int i = 0; i < 16; ++i) acc[i] = 0.f;
    for (int row = wave; row < NQ; row += nw) {
        const float4* rp = reinterpret_cast<const float4*>(in + (size_t)row * NC);
#pragma unroll
        for (int k = 0; k < 4; ++k) {
            int c4 = k * 64 + lane;
            if (c4 < NC4) {
                float4 a = rp[c4];
                acc[4 * k + 0] += __expf(2.0f * a.x);
                acc[4 * k + 1] += __expf(2.0f * a.y);
                acc[4 * k + 2] += __expf(2.0f * a.z);
                acc[4 * k + 3] += __expf(2.0f * a.w);
            }
        }
    }
#pragma unroll
    for (int k = 0; k < 4; ++k) {
        int c4 = k * 64 + lane;
        if (c4 < NC4) {
            atomicAdd(&sacc[4 * c4 + 0], acc[4 * k + 0]);
            atomicAdd(&sacc[4 * c4 + 1], acc[4 * k + 1]);
            atomicAdd(&sacc[4 * c4 + 2], acc[4 * k + 2]);
            atomicAdd(&sacc[4 * c4 + 3], acc[4 * k + 3]);
        }
    }
    __syncthreads();
    for (int i = threadIdx.x; i < NC; i += 256) atomicAdd(&S[i], sacc[i]);
}

// Tiny: stable descending rank of S0, K = softmax(w*log(sigmoid(k))),
// Kscale[c] = K[rank(c)], R1[c] = Kscale[c]/S0[c].
__global__ __launch_bounds__(1024) void k_rank(const float* __restrict__ S,
                                               const float* __restrict__ learn_k,
                                               float* __restrict__ Ksc,
                                               float* __restrict__ R) {
    __shared__ float sS[NC];
    __shared__ float sred[16];
    const int tid = threadIdx.x;
    for (int i = tid; i < NC; i += 1024) sS[i] = S[i];
    __syncthreads();
    const float L = -log1pf(expf(-learn_k[0]));  // log(sigmoid(k)), always <= 0
    // denom = sum_i exp(w_i * L); max of w_i*L is 0 (i=0), matching softmax.
    float part = 0.f;
    for (int i = tid; i < NC; i += 1024)
        part += expf(((float)i * (1.0f / 999.0f)) * L);
    part = wredsum(part);
    if ((tid & 63) == 0) sred[tid >> 6] = part;
    __syncthreads();
    if (tid == 0) {
        float s = 0.f;
        for (int i = 0; i < 16; ++i) s += sred[i];
        sred[0] = s;
    }
    __syncthreads();
    const float denom = sred[0];
    for (int c = tid; c < NC; c += 1024) {
        float sc = sS[c];
        int p = 0;
        for (int j = 0; j < NC; ++j) {
            float sj = sS[j];
            p += (sj > sc) || (sj == sc && j < c);  // stable descending rank
        }
        float ks = expf(((float)p * (1.0f / 999.0f)) * L) / denom;
        Ksc[c] = ks;
        R[c] = ks / sc;
    }
}

__global__ __launch_bounds__(256) void k_prepR(const float* __restrict__ Ksc,
                                               const float* __restrict__ S,
                                               float* __restrict__ R) {
    int i = blockIdx.x * blockDim.x + threadIdx.x;
    if (i < NC) R[i] = Ksc[i] / S[i];
}

// Fused Sinkhorn iteration: v = clip(a*R_c, 1e-16); T = row(queue) sum;
// write v/T; accumulate next cluster sums. One wave owns one queue-row.
template <bool EXPIN, bool ACC>
__global__ __launch_bounds__(256) void k_iter(const float* __restrict__ in,
                                              float* __restrict__ out,
                                              const float* __restrict__ R,
                                              float* __restrict__ Snext) {
    __shared__ float sacc[NC];
    if (ACC) {
        for (int i = threadIdx.x; i < NC; i += 256) sacc[i] = 0.f;
        __syncthreads();
    }
    const int lane = threadIdx.x & 63;
    const int nw = (gridDim.x * 256) >> 6;
    const int wave = (blockIdx.x * 256 + threadIdx.x) >> 6;

    float4 rf[4];
    const float4* R4 = reinterpret_cast<const float4*>(R);
#pragma unroll
    for (int k = 0; k < 4; ++k) {
        int c4 = k * 64 + lane;
        rf[k] = (c4 < NC4) ? R4[c4] : make_float4(0.f, 0.f, 0.f, 0.f);
    }
    float acc[16];
#pragma unroll
    for (int i = 0; i < 16; ++i) acc[i] = 0.f;

    float4 nxt[4];
#pragma unroll
    for (int k = 0; k < 4; ++k) nxt[k] = make_float4(0.f, 0.f, 0.f, 0.f);

    int row = wave;
    if (row < NQ) {
        const float4* rp = reinterpret_cast<const float4*>(in + (size_t)row * NC);
#pragma unroll
        for (int k = 0; k < 4; ++k) {
            int c4 = k * 64 + lane;
            if (c4 < NC4) nxt[k] = rp[c4];
        }
    }
    while (row < NQ) {
        float4 cur[4];
#pragma unroll
        for (int k = 0; k < 4; ++k) cur[k] = nxt[k];
        const int nrow = row + nw;
        if (nrow < NQ) {  // prefetch next row before compute
            const float4* rp = reinterpret_cast<const float4*>(in + (size_t)nrow * NC);
#pragma unroll
            for (int k = 0; k < 4; ++k) {
                int c4 = k * 64 + lane;
                if (c4 < NC4) nxt[k] = rp[c4];
            }
        }
        float t = 0.f;
#pragma unroll
        for (int k = 0; k < 4; ++k) {
            int c4 = k * 64 + lane;
            if (c4 < NC4) {
                float vx = cur[k].x, vy = cur[k].y, vz = cur[k].z, vw = cur[k].w;
                if (EXPIN) {
                    vx = __expf(2.0f * vx); vy = __expf(2.0f * vy);
                    vz = __expf(2.0f * vz); vw = __expf(2.0f * vw);
                }
                vx = fmaxf(vx * rf[k].x, 1e-16f);
                vy = fmaxf(vy * rf[k].y, 1e-16f);
                vz = fmaxf(vz * rf[k].z, 1e-16f);
                vw = fmaxf(vw * rf[k].w, 1e-16f);
                cur[k] = make_float4(vx, vy, vz, vw);
                t += (vx + vy) + (vz + vw);
            }
        }
        t = wredsum(t);
        const float invt = 1.0f / t;
        float4* op = reinterpret_cast<float4*>(out + (size_t)row * NC);
#pragma unroll
        for (int k = 0; k < 4; ++k) {
            int c4 = k * 64 + lane;
            if (c4 < NC4) {
                float wx = cur[k].x * invt, wy = cur[k].y * invt;
                float wz = cur[k].z * invt, ww = cur[k].w * invt;
                op[c4] = make_float4(wx, wy, wz, ww);
                if (ACC) {
                    acc[4 * k + 0] += wx; acc[4 * k + 1] += wy;
                    acc[4 * k + 2] += wz; acc[4 * k + 3] += ww;
                }
            }
        }
        row = nrow;
    }
    if (ACC) {
#pragma unroll
        for (int k = 0; k < 4; ++k) {
            int c4 = k * 64 + lane;
            if (c4 < NC4) {
                atomicAdd(&sacc[4 * c4 + 0], acc[4 * k + 0]);
                atomicAdd(&sacc[4 * c4 + 1], acc[4 * k + 1]);
                atomicAdd(&sacc[4 * c4 + 2], acc[4 * k + 2]);
                atomicAdd(&sacc[4 * c4 + 3], acc[4 * k + 3]);
            }
        }
        __syncthreads();
        for (int i = threadIdx.x; i < NC; i += 256) atomicAdd(&Snext[i], sacc[i]);
    }
}

extern "C" void kernel_launch(void* const* d_in, const int* in_sizes, int n_in,
                              void* d_out, int out_size, void* d_ws, size_t ws_size,
                              hipStream_t stream) {
    const float* logits = (const float*)d_in[0];
    const float* learn_k = (const float*)d_in[1];
    float* out = (float*)d_out;
    float* ws = (float*)d_ws;
    float* S0 = ws;            // [1000] pad to 1024
    float* S1 = ws + 1024;
    float* S2 = ws + 2048;
    float* Ksc = ws + 3072;
    float* R = ws + 4096;

    hipMemsetAsync(ws, 0, 3072 * sizeof(float), stream);  // zero S0,S1,S2

    const int blocks = 1024;
    k_colsum_exp<<<blocks, 256, 0, stream>>>(logits, S0);
    k_rank<<<1, 1024, 0, stream>>>(S0, learn_k, Ksc, R);
    k_iter<true, true><<<blocks, 256, 0, stream>>>(logits, out, R, S1);
    k_prepR<<<4, 256, 0, stream>>>(Ksc, S1, R);
    k_iter<false, true><<<blocks, 256, 0, stream>>>(out, out, R, S2);
    k_prepR<<<4, 256, 0, stream>>>(Ksc, S2, R);
    k_iter<false, false><<<blocks, 256, 0, stream>>>(out, out, R, nullptr);
}